// Round 1
// baseline (125.207 us; speedup 1.0000x reference)
//
#include <hip/hip_runtime.h>
#include <stdint.h>

#define KROWS 8192
#define DDIM  768
#define NUMG  256
#define BM    128
#define BK    64
#define MARGIN_F 0.1f

typedef short bf16x8 __attribute__((ext_vector_type(8)));
typedef float f32x4 __attribute__((ext_vector_type(4)));
typedef unsigned short u16x8 __attribute__((ext_vector_type(8)));

typedef __attribute__((address_space(3))) unsigned char lds_byte;
typedef __attribute__((address_space(1))) const unsigned char glob_byte;

__device__ __forceinline__ uint32_t enc_f32(float f) {
  uint32_t b = __float_as_uint(f);
  return (b & 0x80000000u) ? ~b : (b | 0x80000000u);
}
__device__ __forceinline__ float dec_f32(uint32_t u) {
  uint32_t b = (u & 0x80000000u) ? (u & 0x7FFFFFFFu) : ~u;
  return __uint_as_float(b);
}
__device__ __forceinline__ unsigned short f2bf(float f) {
  uint32_t b = __float_as_uint(f);
  uint32_t r = (b + 0x7FFFu + ((b >> 16) & 1u)) >> 16;
  return (unsigned short)r;
}

// ---------------- init: zero group arrays ----------------
__global__ void init_k(uint32_t* __restrict__ gmin, uint32_t* __restrict__ gmax,
                       int* __restrict__ counts) {
  int t = threadIdx.x;
  gmin[t] = 0xFFFFFFFFu;  // encodes +max
  gmax[t] = 0u;           // encodes -max
  counts[t] = 0;
}

// ---------------- extract group ids + counts ----------------
__global__ void extract_k(const int* __restrict__ pidx, int* __restrict__ gids,
                          int* __restrict__ counts) {
  int t = blockIdx.x * blockDim.x + threadIdx.x;
  if (t < KROWS) {
    int g = pidx[2 * t + 1] & (NUMG - 1);
    gids[t] = g;
    atomicAdd(&counts[g], 1);
  }
}

// ---------------- f32 -> bf16 convert (8 elems/thread) ----------------
__global__ void convert_k(const float* __restrict__ x, unsigned short* __restrict__ xb) {
  int t = blockIdx.x * blockDim.x + threadIdx.x;  // KROWS*DDIM/8 threads
  const float4* p = reinterpret_cast<const float4*>(x + 8 * (size_t)t);
  float4 a = p[0], b = p[1];
  u16x8 r;
  r[0] = f2bf(a.x); r[1] = f2bf(a.y); r[2] = f2bf(a.z); r[3] = f2bf(a.w);
  r[4] = f2bf(b.x); r[5] = f2bf(b.y); r[6] = f2bf(b.z); r[7] = f2bf(b.w);
  *reinterpret_cast<u16x8*>(xb + 8 * (size_t)t) = r;
}

// ---------------- main fused Gram + margin-reduce kernel ----------------
// Lower-triangle tiles only (ib >= jb). 128x128 tile, BK=64, 4 waves (2x2),
// each wave 64x64 = 4x4 fragments of 16x16x32 bf16 MFMA.
// LDS tiles XOR-swizzled (byte ^= (row&7)<<4) via pre-swizzled global source.
__launch_bounds__(256, 2)
__global__ void gram_margin_k(const unsigned short* __restrict__ xb,
                              const int* __restrict__ gids,
                              uint32_t* __restrict__ gmin,
                              uint32_t* __restrict__ gmax) {
  __shared__ unsigned short sA[BM * BK];
  __shared__ unsigned short sB[BM * BK];
  __shared__ uint32_t lgmin[NUMG];
  __shared__ uint32_t lgmax[NUMG];
  __shared__ int sgr[BM];
  __shared__ int sgc[BM];

  const int tid  = threadIdx.x;
  const int lane = tid & 63;
  const int wid  = tid >> 6;
  const int wr   = wid >> 1, wc = wid & 1;
  const int lr   = lane & 15, lh = lane >> 4;

  // decode triangular block index -> (ib, jb), ib >= jb
  int bid = blockIdx.x;
  int ib = (int)((sqrtf(8.0f * (float)bid + 1.0f) - 1.0f) * 0.5f);
  while ((ib + 1) * (ib + 2) / 2 <= bid) ++ib;
  while (ib * (ib + 1) / 2 > bid) --ib;
  int jb = bid - ib * (ib + 1) / 2;
  const int i0 = ib * BM, j0 = jb * BM;

  if (tid < NUMG) { lgmin[tid] = 0xFFFFFFFFu; lgmax[tid] = 0u; }
  if (tid < BM)   { sgr[tid] = gids[i0 + tid]; sgc[tid] = gids[j0 + tid]; }

  f32x4 acc[4][4];
  const f32x4 zz = {0.f, 0.f, 0.f, 0.f};
#pragma unroll
  for (int m = 0; m < 4; ++m)
#pragma unroll
    for (int n = 0; n < 4; ++n) acc[m][n] = zz;

  const int srow = tid >> 3;   // 0..31 (row within 32-row staging chunk)
  const int schunk = tid & 7;  // 16B chunk within 128B row

  for (int kt = 0; kt < DDIM / BK; ++kt) {
    const int k0 = kt * BK;
#pragma unroll
    for (int c = 0; c < 4; ++c) {
      int row = c * 32 + srow;
      int chunk = schunk ^ (row & 7);  // pre-swizzle global source
      const unsigned short* ga = xb + (size_t)(i0 + row) * DDIM + k0 + chunk * 8;
      const unsigned short* gb = xb + (size_t)(j0 + row) * DDIM + k0 + chunk * 8;
      unsigned short* la = sA + c * 2048 + tid * 8;
      unsigned short* lb = sB + c * 2048 + tid * 8;
      __builtin_amdgcn_global_load_lds((glob_byte*)ga, (lds_byte*)la, 16, 0, 0);
      __builtin_amdgcn_global_load_lds((glob_byte*)gb, (lds_byte*)lb, 16, 0, 0);
    }
    __syncthreads();
#pragma unroll
    for (int ks = 0; ks < 2; ++ks) {
      bf16x8 af[4], bfr[4];
#pragma unroll
      for (int m = 0; m < 4; ++m) {
        int row = wr * 64 + m * 16 + lr;
        int byteoff = row * 128 + ((lh * 16 + ks * 64) ^ ((row & 7) << 4));
        af[m] = *reinterpret_cast<const bf16x8*>(
            reinterpret_cast<const char*>(sA) + byteoff);
      }
#pragma unroll
      for (int n = 0; n < 4; ++n) {
        int row = wc * 64 + n * 16 + lr;
        int byteoff = row * 128 + ((lh * 16 + ks * 64) ^ ((row & 7) << 4));
        bfr[n] = *reinterpret_cast<const bf16x8*>(
            reinterpret_cast<const char*>(sB) + byteoff);
      }
#pragma unroll
      for (int m = 0; m < 4; ++m)
#pragma unroll
        for (int n = 0; n < 4; ++n)
          acc[m][n] = __builtin_amdgcn_mfma_f32_16x16x32_bf16(af[m], bfr[n],
                                                              acc[m][n], 0, 0, 0);
    }
    __syncthreads();
  }

  // ---------------- fused epilogue ----------------
  // C/D layout: col = lane&15, row = (lane>>4)*4 + reg  [m89-verified]
  int gi[4][4];
#pragma unroll
  for (int m = 0; m < 4; ++m)
#pragma unroll
    for (int r = 0; r < 4; ++r) gi[m][r] = sgr[wr * 64 + m * 16 + lh * 4 + r];
  int gj[4];
#pragma unroll
  for (int n = 0; n < 4; ++n) gj[n] = sgc[wc * 64 + n * 16 + lr];

  float rmin[4][4], rmax[4][4], cmax[4];
#pragma unroll
  for (int m = 0; m < 4; ++m)
#pragma unroll
    for (int r = 0; r < 4; ++r) { rmin[m][r] = 3.0e38f; rmax[m][r] = -3.0e38f; }
#pragma unroll
  for (int n = 0; n < 4; ++n) cmax[n] = -3.0e38f;

  const bool offdiag = (ib != jb);
#pragma unroll
  for (int m = 0; m < 4; ++m) {
#pragma unroll
    for (int r = 0; r < 4; ++r) {
      int ii = i0 + wr * 64 + m * 16 + lh * 4 + r;
#pragma unroll
      for (int n = 0; n < 4; ++n) {
        int jj = j0 + wc * 64 + n * 16 + lr;
        float s = acc[m][n][r];
        if (offdiag || (ii > jj)) {
          if (gi[m][r] == gj[n]) {
            rmin[m][r] = fminf(rmin[m][r], s);
          } else {
            rmax[m][r] = fmaxf(rmax[m][r], s);
            cmax[n] = fmaxf(cmax[n], s);
          }
        }
      }
    }
  }

  // reduce rows across the 16 j-lanes (xor 1,2,4,8)
#pragma unroll
  for (int s = 1; s <= 8; s <<= 1) {
#pragma unroll
    for (int m = 0; m < 4; ++m)
#pragma unroll
      for (int r = 0; r < 4; ++r) {
        rmin[m][r] = fminf(rmin[m][r], __shfl_xor(rmin[m][r], s, 64));
        rmax[m][r] = fmaxf(rmax[m][r], __shfl_xor(rmax[m][r], s, 64));
      }
  }
  // reduce cols across the 4 i-lane-groups (xor 16, 32)
#pragma unroll
  for (int s = 16; s <= 32; s <<= 1)
#pragma unroll
    for (int n = 0; n < 4; ++n)
      cmax[n] = fmaxf(cmax[n], __shfl_xor(cmax[n], s, 64));

  if (lr == 0) {
#pragma unroll
    for (int m = 0; m < 4; ++m)
#pragma unroll
      for (int r = 0; r < 4; ++r) {
        if (rmin[m][r] < 1.0e38f) atomicMin(&lgmin[gi[m][r]], enc_f32(rmin[m][r]));
        if (rmax[m][r] > -1.0e38f) atomicMax(&lgmax[gi[m][r]], enc_f32(rmax[m][r]));
      }
  }
  if (lh == 0) {
#pragma unroll
    for (int n = 0; n < 4; ++n)
      if (cmax[n] > -1.0e38f) atomicMax(&lgmax[gj[n]], enc_f32(cmax[n]));
  }
  __syncthreads();

  // merge block-local group arrays to global (tid covers all 256 groups)
  {
    uint32_t mn = lgmin[tid], mx = lgmax[tid];
    if (mn != 0xFFFFFFFFu) atomicMin(&gmin[tid], mn);
    if (mx != 0u) atomicMax(&gmax[tid], mx);
  }
}

// ---------------- finalize: per-group margin + mean ----------------
__global__ void finalize_k(const uint32_t* __restrict__ gmin,
                           const uint32_t* __restrict__ gmax,
                           const int* __restrict__ counts,
                           float* __restrict__ out) {
  __shared__ float s_num[256];
  __shared__ float s_den[256];
  int t = threadIdx.x;
  float per = 0.f, ne = 0.f;
  if (counts[t] > 0) {
    ne = 1.f;
    float mn = (gmin[t] == 0xFFFFFFFFu) ? 1.0e9f : dec_f32(gmin[t]);
    float mx = (gmax[t] == 0u) ? -1.0e9f : dec_f32(gmax[t]);
    per = fmaxf(0.0f, mx - mn + MARGIN_F);
  }
  s_num[t] = per;
  s_den[t] = ne;
  __syncthreads();
  for (int s = 128; s > 0; s >>= 1) {
    if (t < s) { s_num[t] += s_num[t + s]; s_den[t] += s_den[t + s]; }
    __syncthreads();
  }
  if (t == 0) out[0] = s_num[0] / s_den[0];
}

extern "C" void kernel_launch(void* const* d_in, const int* in_sizes, int n_in,
                              void* d_out, int out_size, void* d_ws, size_t ws_size,
                              hipStream_t stream) {
  const float* x   = (const float*)d_in[0];
  const int* pidx  = (const int*)d_in[1];
  float* out       = (float*)d_out;

  char* ws = (char*)d_ws;
  unsigned short* xb = (unsigned short*)ws;
  size_t off = (size_t)KROWS * DDIM * 2;          // 12,582,912 B
  int* gids      = (int*)(ws + off); off += (size_t)KROWS * 4;
  int* counts    = (int*)(ws + off); off += NUMG * 4;
  uint32_t* gmin = (uint32_t*)(ws + off); off += NUMG * 4;
  uint32_t* gmax = (uint32_t*)(ws + off); off += NUMG * 4;

  hipLaunchKernelGGL(init_k, dim3(1), dim3(NUMG), 0, stream, gmin, gmax, counts);
  hipLaunchKernelGGL(extract_k, dim3(KROWS / 256), dim3(256), 0, stream,
                     pidx, gids, counts);
  hipLaunchKernelGGL(convert_k, dim3((KROWS * DDIM / 8) / 256), dim3(256), 0, stream,
                     x, xb);
  const int ntiles = KROWS / BM;                  // 64
  hipLaunchKernelGGL(gram_margin_k, dim3(ntiles * (ntiles + 1) / 2), dim3(256), 0,
                     stream, xb, gids, gmin, gmax);
  hipLaunchKernelGGL(finalize_k, dim3(1), dim3(NUMG), 0, stream,
                     gmin, gmax, counts, out);
}